// Round 2
// baseline (285.497 us; speedup 1.0000x reference)
//
#include <hip/hip_runtime.h>
#include <hip/hip_bf16.h>

// GlobalFilter: y = irfft2(rfft2(x, ortho) * W, ortho)  ==  per-channel 14x14
// circular convolution with kernel R_c = (1/196) * Re(IFFT2(Wext_c)).
//
// x: (256, 196, 512) fp32, W: (14, 8, 512, 2) fp32, out: (256, 196, 512) fp32.
//
// ws layout: R  at offset 0            : 196*512 floats  (401,408 B)
//               *** pair layout ***: R[((dm*7 + dn/2)*512 + c)*2 + (dn&1)]
//            T  at offset 196*512      : 14*14*512*2 floats (802,816 B)  [complex]
// (recomputed every launch; ws is re-poisoned by the harness)

#define Hs 14
#define Ns 196          // 14*14
#define Cc 512
#define CT 32           // channel tile
#define CONV_THREADS 448  // 32 c x 14 rows; v2f lanes carry the 2 batches

typedef float v2f __attribute__((ext_vector_type(2)));

// ---------------------------------------------------------------------------
// Prep stage A:  T[h][dn][c] = sum_{w=0..7} W[h,w,c]   * z^{+w*dn}
//                            + sum_{w=1..6} conj(W[h2,w,c]) * z^{-w*dn}
// with z = e^{i*2pi/14}, h2 = (14-h)%14.  (This is sum_w Wext[h,w,c] z^{w*dn}.)
// ---------------------------------------------------------------------------
__global__ __launch_bounds__(256) void prep_a_kernel(const float* __restrict__ cw,
                                                     float* __restrict__ T) {
    __shared__ float cs[14], sn[14];
    if (threadIdx.x < 14) {
        float ang = (float)threadIdx.x * 0.44879895051282760549f;  // 2*pi/14
        cs[threadIdx.x] = cosf(ang);
        sn[threadIdx.x] = sinf(ang);
    }
    __syncthreads();

    int gid = blockIdx.x * 256 + threadIdx.x;   // 14*14*512 = 100352 = 392*256
    int c = gid & 511;
    int s = gid >> 9;          // h*14 + dn
    int h = s / 14;
    int dn = s % 14;
    int h2 = (h == 0) ? 0 : (14 - h);

    float Tr = 0.0f, Ti = 0.0f;
    // w = 0..7 (direct terms), angle +w*dn
    int k = 0;
    #pragma unroll
    for (int w = 0; w < 8; ++w) {
        const float* p = cw + (size_t)(((h * 8 + w) * 512 + c) * 2);
        float Wr = p[0], Wi = p[1];
        Tr += Wr * cs[k] - Wi * sn[k];
        Ti += Wr * sn[k] + Wi * cs[k];
        k += dn; if (k >= 14) k -= 14;
    }
    // w = 1..6 (mirror terms): conj(W[h2,w,c]) * (cs[k] - i*sn[k])
    int k2 = dn; if (k2 >= 14) k2 -= 14;
    #pragma unroll
    for (int w = 1; w < 7; ++w) {
        const float* p = cw + (size_t)(((h2 * 8 + w) * 512 + c) * 2);
        float Wr = p[0], Wi = p[1];
        Tr += Wr * cs[k2] - Wi * sn[k2];
        Ti -= Wr * sn[k2] + Wi * cs[k2];
        k2 += dn; if (k2 >= 14) k2 -= 14;
    }
    float* o = T + (size_t)(s * 512 + c) * 2;
    o[0] = Tr;
    o[1] = Ti;
}

// ---------------------------------------------------------------------------
// Prep stage B:  Rval(dm,dn,c) = (1/196) * sum_h (Tr[h,dn,c]*cs[(h*dm)%14]
//                                                - Ti[h,dn,c]*sn[(h*dm)%14])
// Output in PAIR layout: R[((dm*7 + dn/2)*512 + c)*2 + (dn&1)], so the conv
// kernel can ds_read_b64 {R(dm,2j), R(dm,2j+1)} and op_sel-broadcast halves.
// ---------------------------------------------------------------------------
__global__ __launch_bounds__(256) void prep_b_kernel(const float* __restrict__ T,
                                                     float* __restrict__ R) {
    __shared__ float cs[14], sn[14];
    if (threadIdx.x < 14) {
        float ang = (float)threadIdx.x * 0.44879895051282760549f;  // 2*pi/14
        cs[threadIdx.x] = cosf(ang);
        sn[threadIdx.x] = sinf(ang);
    }
    __syncthreads();

    int gid = blockIdx.x * 256 + threadIdx.x;   // 196*512
    int c = gid & 511;
    int s = gid >> 9;          // dm*14 + dn
    int dm = s / 14;
    int dn = s % 14;

    float acc = 0.0f;
    int kh = 0;
    #pragma unroll
    for (int h = 0; h < 14; ++h) {
        const float* p = T + (size_t)(((h * 14 + dn) * 512 + c) * 2);
        acc += p[0] * cs[kh] - p[1] * sn[kh];
        kh += dm; if (kh >= 14) kh -= 14;
    }
    R[(size_t)(((dm * 7 + (dn >> 1)) * 512 + c) * 2 + (dn & 1))] = acc * (1.0f / 196.0f);
}

// ---------------------------------------------------------------------------
// Main conv: block = 2 batches x 32-channel tile. 448 threads:
//   c = tid&31, m = tid>>5 (0..13). Each thread computes row m (all 14 n) for
//   BOTH batches of the pair, packed as v2f: acc[n] = (y[b0,m,n], y[b1,m,n]).
//   x staged batch-paired in LDS (ds_read_b64, broadcast across half-waves);
//   R staged dn-paired (ds_read_b64); the FMA is a guaranteed v_pk_fma_f32
//   with op_sel broadcasting the correct 32-bit half of the R pair:
//     dn even -> src1.lo to both lanes:  op_sel:[0,0,0] op_sel_hi:[1,0,1]
//     dn odd  -> src1.hi to both lanes:  op_sel:[0,1,0] op_sel_hi:[1,1,1]
//   Peak live set: acc 28 + rv2 14 + xv 2 + bases ~ 48 VGPR (fits regalloc's
//   observed 52-reg appetite -> nothing can be demoted to LDS re-reads).
// ---------------------------------------------------------------------------
__global__ __launch_bounds__(CONV_THREADS, 3) void conv_kernel(
        const float* __restrict__ x,
        const float* __restrict__ R,
        float* __restrict__ out) {
    __shared__ v2f xs2[Ns * CT];        // 50,176 B  (batch-paired x)
    __shared__ v2f rs2[98 * CT];        // 25,088 B  (dn-paired R)

    const int bx = blockIdx.x;          // 2048 blocks
    const int ct = bx & 15;             // 16 channel tiles of 32
    const int bp = bx >> 4;             // 0..127 batch pairs
    const int c0 = ct * CT;
    const int b0 = bp * 2;
    const int t  = threadIdx.x;

    const float* xb = x + (size_t)b0 * Ns * Cc + c0;
    const v2f*  Rbv = (const v2f*)R + c0;          // pair units, channel offset
    // cooperative load: x = 6272 v2f (14 iters), R = 3136 v2f (7 iters)
    for (int i = t; i < Ns * CT; i += CONV_THREADS) {
        int pq = i >> 5;
        int cc = i & (CT - 1);
        v2f v;
        v.x = xb[pq * Cc + cc];
        v.y = xb[(size_t)Ns * Cc + pq * Cc + cc];
        xs2[i] = v;
    }
    for (int i = t; i < 98 * CT; i += CONV_THREADS) {
        rs2[i] = Rbv[(i >> 5) * Cc + (i & (CT - 1))];
    }
    __syncthreads();

    const int c = t & (CT - 1);
    const int m = t >> 5;               // 0..13

    v2f acc[14];
    #pragma unroll
    for (int n = 0; n < 14; ++n) acc[n] = 0.0f;

    #pragma unroll 1
    for (int p = 0; p < 14; ++p) {
        int dm = m - p; if (dm < 0) dm += 14;
        const v2f* xrow = xs2 + p  * 14 * CT + c;
        const v2f* rrow = rs2 + dm * 7  * CT + c;

        v2f rv2[7];                     // {R(dm,2j), R(dm,2j+1)}
        #pragma unroll
        for (int j = 0; j < 7; ++j) rv2[j] = rrow[j * CT];

        #pragma unroll
        for (int q = 0; q < 14; ++q) {
            v2f xv = xrow[q * CT];
            #pragma unroll
            for (int n = 0; n < 14; ++n) {
                const int dn = (n - q + 14) % 14;      // compile-time constant
                v2f rp = rv2[dn >> 1];
                if (dn & 1) {
                    // both lanes use rp.hi
                    asm("v_pk_fma_f32 %0, %1, %2, %0 op_sel:[0,1,0] op_sel_hi:[1,1,1]"
                        : "+v"(acc[n]) : "v"(xv), "v"(rp));
                } else {
                    // both lanes use rp.lo
                    asm("v_pk_fma_f32 %0, %1, %2, %0 op_sel:[0,0,0] op_sel_hi:[1,0,1]"
                        : "+v"(acc[n]) : "v"(xv), "v"(rp));
                }
            }
        }
    }

    float* o0 = out + ((size_t)b0 * Ns + m * 14) * Cc + c0 + c;
    float* o1 = o0 + (size_t)Ns * Cc;
    #pragma unroll
    for (int n = 0; n < 14; ++n) {
        o0[n * Cc] = acc[n].x;
        o1[n * Cc] = acc[n].y;
    }
}

extern "C" void kernel_launch(void* const* d_in, const int* in_sizes, int n_in,
                              void* d_out, int out_size, void* d_ws, size_t ws_size,
                              hipStream_t stream) {
    const float* x  = (const float*)d_in[0];
    const float* cw = (const float*)d_in[1];
    float* outp = (float*)d_out;
    float* R = (float*)d_ws;                    // 196*512 floats (pair layout)
    float* T = R + (size_t)Ns * Cc;             // 14*14*512*2 floats

    prep_a_kernel<<<392, 256, 0, stream>>>(cw, T);
    prep_b_kernel<<<392, 256, 0, stream>>>(T, R);
    conv_kernel<<<128 * 16, CONV_THREADS, 0, stream>>>(x, R, outp);
}

// Round 3
// 270.611 us; speedup vs baseline: 1.0550x; 1.0550x over previous
//
#include <hip/hip_runtime.h>
#include <hip/hip_fp16.h>

// GlobalFilter: y = irfft2(rfft2(x, ortho) * W, ortho)  ==  per-channel 14x14
// circular convolution with kernel R_c = (1/196) * Re(IFFT2(Wext_c)).
//
// x: (256, 196, 512) fp32, W: (14, 8, 512, 2) fp32, out: (256, 196, 512) fp32.
//
// ws layout: R  at offset 0            : 196*512 floats  (401,408 B)
//               *** pair layout ***: R[((dm*7 + dn/2)*512 + c)*2 + (dn&1)]
//            T  at offset 196*512      : 14*14*512*2 floats (802,816 B)  [complex]
// (recomputed every launch; ws is re-poisoned by the harness)

#define Hs 14
#define Ns 196          // 14*14
#define Cc 512
#define CT 32           // channel tile
#define CONV_THREADS 448  // 32 c x 14 rows; v2f lanes carry the 2 batches

typedef float v2f __attribute__((ext_vector_type(2)));

// ---------------------------------------------------------------------------
// Prep stage A:  T[h][dn][c] = sum_{w=0..7} W[h,w,c]   * z^{+w*dn}
//                            + sum_{w=1..6} conj(W[h2,w,c]) * z^{-w*dn}
// with z = e^{i*2pi/14}, h2 = (14-h)%14.  (This is sum_w Wext[h,w,c] z^{w*dn}.)
// ---------------------------------------------------------------------------
__global__ __launch_bounds__(256) void prep_a_kernel(const float* __restrict__ cw,
                                                     float* __restrict__ T) {
    __shared__ float cs[14], sn[14];
    if (threadIdx.x < 14) {
        float ang = (float)threadIdx.x * 0.44879895051282760549f;  // 2*pi/14
        cs[threadIdx.x] = cosf(ang);
        sn[threadIdx.x] = sinf(ang);
    }
    __syncthreads();

    int gid = blockIdx.x * 256 + threadIdx.x;   // 14*14*512 = 100352 = 392*256
    int c = gid & 511;
    int s = gid >> 9;          // h*14 + dn
    int h = s / 14;
    int dn = s % 14;
    int h2 = (h == 0) ? 0 : (14 - h);

    float Tr = 0.0f, Ti = 0.0f;
    // w = 0..7 (direct terms), angle +w*dn
    int k = 0;
    #pragma unroll
    for (int w = 0; w < 8; ++w) {
        const float* p = cw + (size_t)(((h * 8 + w) * 512 + c) * 2);
        float Wr = p[0], Wi = p[1];
        Tr += Wr * cs[k] - Wi * sn[k];
        Ti += Wr * sn[k] + Wi * cs[k];
        k += dn; if (k >= 14) k -= 14;
    }
    // w = 1..6 (mirror terms): conj(W[h2,w,c]) * (cs[k] - i*sn[k])
    int k2 = dn; if (k2 >= 14) k2 -= 14;
    #pragma unroll
    for (int w = 1; w < 7; ++w) {
        const float* p = cw + (size_t)(((h2 * 8 + w) * 512 + c) * 2);
        float Wr = p[0], Wi = p[1];
        Tr += Wr * cs[k2] - Wi * sn[k2];
        Ti -= Wr * sn[k2] + Wi * cs[k2];
        k2 += dn; if (k2 >= 14) k2 -= 14;
    }
    float* o = T + (size_t)(s * 512 + c) * 2;
    o[0] = Tr;
    o[1] = Ti;
}

// ---------------------------------------------------------------------------
// Prep stage B:  Rval(dm,dn,c) = (1/196) * sum_h (Tr[h,dn,c]*cs[(h*dm)%14]
//                                                - Ti[h,dn,c]*sn[(h*dm)%14])
// Output in PAIR layout: R[((dm*7 + dn/2)*512 + c)*2 + (dn&1)], so the conv
// kernel can load {R(dm,2j), R(dm,2j+1)} as one unit.
// ---------------------------------------------------------------------------
__global__ __launch_bounds__(256) void prep_b_kernel(const float* __restrict__ T,
                                                     float* __restrict__ R) {
    __shared__ float cs[14], sn[14];
    if (threadIdx.x < 14) {
        float ang = (float)threadIdx.x * 0.44879895051282760549f;  // 2*pi/14
        cs[threadIdx.x] = cosf(ang);
        sn[threadIdx.x] = sinf(ang);
    }
    __syncthreads();

    int gid = blockIdx.x * 256 + threadIdx.x;   // 196*512
    int c = gid & 511;
    int s = gid >> 9;          // dm*14 + dn
    int dm = s / 14;
    int dn = s % 14;

    float acc = 0.0f;
    int kh = 0;
    #pragma unroll
    for (int h = 0; h < 14; ++h) {
        const float* p = T + (size_t)(((h * 14 + dn) * 512 + c) * 2);
        acc += p[0] * cs[kh] - p[1] * sn[kh];
        kh += dm; if (kh >= 14) kh -= 14;
    }
    R[(size_t)(((dm * 7 + (dn >> 1)) * 512 + c) * 2 + (dn & 1))] = acc * (1.0f / 196.0f);
}

// ---------------------------------------------------------------------------
// Main conv: block = 2 batches x 32-channel tile. 448 threads:
//   c = tid&31, m = tid>>5 (0..13). Each thread computes row m (all 14 n) for
//   BOTH batches of the pair, packed as v2f: acc[n] = (y[b0,m,n], y[b1,m,n]).
//
//   Round-3 change: LDS staged in FP16 (__half2) to halve LDS footprint:
//     xs[pq][c] = half2{x[b0], x[b1]},  rs[(dm,j)][c] = half2{R(dm,2j), R(dm,2j+1)}
//   LDS 75,264 -> 37,632 B  =>  4 blocks/CU (28 waves/CU, 7 waves/SIMD) for
//   2x latency hiding.  DS instr count unchanged (b32 instead of b64).
//   FMA path: verified round-2 op_sel v_pk_fma_f32 (src1 half broadcast):
//     dn even -> rp.lo both lanes:  op_sel:[0,0,0] op_sel_hi:[1,0,1]
//     dn odd  -> rp.hi both lanes:  op_sel:[0,1,0] op_sel_hi:[1,1,1]
// ---------------------------------------------------------------------------
__global__ __launch_bounds__(CONV_THREADS, 7) void conv_kernel(
        const float* __restrict__ x,
        const float* __restrict__ R,
        float* __restrict__ out) {
    __shared__ __half2 xs[Ns * CT];     // 25,088 B  (batch-paired x, fp16)
    __shared__ __half2 rs[98 * CT];     // 12,544 B  (dn-paired R, fp16)

    const int bx = blockIdx.x;          // 2048 blocks
    const int ct = bx & 15;             // 16 channel tiles of 32
    const int bp = bx >> 4;             // 0..127 batch pairs
    const int c0 = ct * CT;
    const int b0 = bp * 2;
    const int t  = threadIdx.x;

    const float* xb = x + (size_t)b0 * Ns * Cc + c0;
    const v2f*  Rbv = (const v2f*)R + c0;          // pair units, channel offset
    // cooperative load: x = 6272 half2 (14 iters), R = 3136 half2 (7 iters)
    for (int i = t; i < Ns * CT; i += CONV_THREADS) {
        int pq = i >> 5;
        int cc = i & (CT - 1);
        float a = xb[pq * Cc + cc];
        float b = xb[(size_t)Ns * Cc + pq * Cc + cc];
        xs[i] = __floats2half2_rn(a, b);
    }
    for (int i = t; i < 98 * CT; i += CONV_THREADS) {
        v2f rp = Rbv[(i >> 5) * Cc + (i & (CT - 1))];
        rs[i] = __floats2half2_rn(rp.x, rp.y);
    }
    __syncthreads();

    const int c = t & (CT - 1);
    const int m = t >> 5;               // 0..13

    v2f acc[14];
    #pragma unroll
    for (int n = 0; n < 14; ++n) acc[n] = 0.0f;

    #pragma unroll 1
    for (int p = 0; p < 14; ++p) {
        int dm = m - p; if (dm < 0) dm += 14;
        const __half2* xrow = xs + p  * 14 * CT + c;
        const __half2* rrow = rs + dm * 7  * CT + c;

        __half2 rv[7];                  // {R(dm,2j), R(dm,2j+1)} fp16
        #pragma unroll
        for (int j = 0; j < 7; ++j) rv[j] = rrow[j * CT];
        __half2 xr[14];                 // {x[b0], x[b1]} fp16
        #pragma unroll
        for (int q = 0; q < 14; ++q) xr[q] = xrow[q * CT];

        v2f rp[7];                      // fp32 pairs (r_even, r_odd)
        #pragma unroll
        for (int j = 0; j < 7; ++j) {
            rp[j].x = __low2float(rv[j]);
            rp[j].y = __high2float(rv[j]);
        }

        #pragma unroll
        for (int q = 0; q < 14; ++q) {
            v2f xv;
            xv.x = __low2float(xr[q]);
            xv.y = __high2float(xr[q]);
            #pragma unroll
            for (int n = 0; n < 14; ++n) {
                const int dn = (n - q + 14) % 14;      // compile-time constant
                v2f rpj = rp[dn >> 1];
                if (dn & 1) {
                    // both lanes use rpj.hi
                    asm("v_pk_fma_f32 %0, %1, %2, %0 op_sel:[0,1,0] op_sel_hi:[1,1,1]"
                        : "+v"(acc[n]) : "v"(xv), "v"(rpj));
                } else {
                    // both lanes use rpj.lo
                    asm("v_pk_fma_f32 %0, %1, %2, %0 op_sel:[0,0,0] op_sel_hi:[1,0,1]"
                        : "+v"(acc[n]) : "v"(xv), "v"(rpj));
                }
            }
        }
    }

    float* o0 = out + ((size_t)b0 * Ns + m * 14) * Cc + c0 + c;
    float* o1 = o0 + (size_t)Ns * Cc;
    #pragma unroll
    for (int n = 0; n < 14; ++n) {
        o0[n * Cc] = acc[n].x;
        o1[n * Cc] = acc[n].y;
    }
}

extern "C" void kernel_launch(void* const* d_in, const int* in_sizes, int n_in,
                              void* d_out, int out_size, void* d_ws, size_t ws_size,
                              hipStream_t stream) {
    const float* x  = (const float*)d_in[0];
    const float* cw = (const float*)d_in[1];
    float* outp = (float*)d_out;
    float* R = (float*)d_ws;                    // 196*512 floats (pair layout)
    float* T = R + (size_t)Ns * Cc;             // 14*14*512*2 floats

    prep_a_kernel<<<392, 256, 0, stream>>>(cw, T);
    prep_b_kernel<<<392, 256, 0, stream>>>(T, R);
    conv_kernel<<<128 * 16, CONV_THREADS, 0, stream>>>(x, R, outp);
}